// Round 7
// baseline (1237.541 us; speedup 1.0000x reference)
//
#include <hip/hip_runtime.h>
#include <hip/hip_bf16.h>

typedef short short8v __attribute__((ext_vector_type(8)));
typedef float float4v __attribute__((ext_vector_type(4)));

constexpr int Bb = 64;    // batch
constexpr int Cc = 32;    // capsules (softmax axis)
constexpr int Nn = 1152;  // routes
constexpr int Oo = 64;    // out channels
constexpr int Ii = 64;    // in channels
constexpr int NCH = 32;   // n-chunks (grid.x)
constexpr int CHN = 36;   // n per chunk (even -> clean 2-unroll)
constexpr int OT  = 16;   // o-tiles (grid.y), 4 o per tile (1 per wave)

__device__ __forceinline__ unsigned short bf16_rne(float f) {
    unsigned u = __float_as_uint(f);
    u += 0x7FFFu + ((u >> 16) & 1u);
    return (unsigned short)(u >> 16);
}
__device__ __forceinline__ float bf16_f(unsigned short h) {
    return __uint_as_float(((unsigned)h) << 16);
}
__device__ __forceinline__ float squash_elem(float s) {
    float sq = s * s;
    return (sq / (1.f + sq)) * s / sqrtf(sq + 1e-8f);
}

// ---- pre-split x into hi/lo bf16 planes (one-time, ~38 MB traffic) ---------
__global__ __launch_bounds__(256) void prep_x(const float* __restrict__ x,
                                              unsigned short* __restrict__ xh,
                                              unsigned short* __restrict__ xl) {
    size_t g = (size_t)blockIdx.x * 256 + threadIdx.x;  // one float4 per thread
    float4 v = ((const float4*)x)[g];
    float a[4] = {v.x, v.y, v.z, v.w};
    ushort4 H, L;
    unsigned short* hp = (unsigned short*)&H;
    unsigned short* lp = (unsigned short*)&L;
#pragma unroll
    for (int e = 0; e < 4; ++e) {
        unsigned short hb = bf16_rne(a[e]);
        hp[e] = hb;
        lp[e] = bf16_rne(a[e] - bf16_f(hb));
    }
    ((ushort4*)xh)[g] = H;
    ((ushort4*)xl)[g] = L;
}

// ---- fused pass: recompute u via split-bf16 MFMA, route, partial-reduce ----
// MODE 0: acc += u; MODE 1: acc += softmax_c(u*V) * u
// Block (n-chunk, o-quad): 64 b x 32 c x 4 o. LDS rows = ol*32 + c so wave wv
// (= ol) reads ONLY its 32-row slice -> B-tile read exactly once per block
// (was 4x in R5). Each wave covers all 64 b via 4 A-blocks from global x.
template <int MODE>
__global__ __launch_bounds__(256, 2) void caps_pass(
    const float* __restrict__ w, const unsigned short* __restrict__ xh,
    const unsigned short* __restrict__ xl, const float* __restrict__ V,
    float* __restrict__ part) {
    __shared__ unsigned short sh[2][128 * 64];  // hi plane, [row][i^swz]
    __shared__ unsigned short sl[2][128 * 64];  // lo plane

    const int t = threadIdx.x;
    const int l = t & 63, wv = t >> 6;   // wv = o_local
    const int ch = blockIdx.x, ot = blockIdx.y;
    const int obase = ot * 4;
    const int o = obase + wv;
    const int kg = l >> 4, lm = l & 15;
    const int n0 = ch * CHN;
    const int sw = (lm & 7) << 3;        // read-side XOR (ushort units)

    // per-lane V: b = 16bq+4kg+r, c = 16t8l+lm, o fixed per wave
    float Vreg[4][2][4];
    if constexpr (MODE == 1) {
#pragma unroll
        for (int bq = 0; bq < 4; ++bq)
#pragma unroll
            for (int t8l = 0; t8l < 2; ++t8l)
#pragma unroll
                for (int r = 0; r < 4; ++r) {
                    int b = 16 * bq + 4 * kg + r;
                    int c = 16 * t8l + lm;
                    Vreg[bq][t8l][r] = V[((size_t)b * Cc + c) * Oo + o];
                }
    }
    float4v acc4[4][2];   // MODE 0 accumulators (chained through MFMA C)
    float accs[4][2][4];  // MODE 1 accumulators
#pragma unroll
    for (int bq = 0; bq < 4; ++bq)
#pragma unroll
        for (int t8l = 0; t8l < 2; ++t8l) {
            acc4[bq][t8l] = (float4v){0.f, 0.f, 0.f, 0.f};
#pragma unroll
            for (int r = 0; r < 4; ++r) accs[bq][t8l][r] = 0.f;
        }

    // staging: per thread 8 cols x 16B; col_lin = (t>>4)+16k, i0 = (t&15)*4
    // global pattern identical to R5 (4 consecutive 256B rows per 4 cols).
    const int i0 = (t & 15) * 4;
    const int colb = t >> 4;
    float4 L0[8], L1[8];

    auto issue = [&](int n, float4(&ld)[8]) {
#pragma unroll
        for (int k = 0; k < 8; ++k) {
            int col = colb + 16 * k;
            int c = col >> 2, olc = col & 3;
            ld[k] = *(const float4*)(
                w + (((size_t)c * Nn + n) * Oo + obase + olc) * Ii + i0);
        }
    };
    auto writebuf = [&](unsigned short* dh, unsigned short* dl,
                        const float4(&ld)[8]) {
#pragma unroll
        for (int k = 0; k < 8; ++k) {
            int col = colb + 16 * k;
            int c = col >> 2, olc = col & 3;
            int row = olc * 32 + c;                        // NEW LDS mapping
            int off = row * 64 + (i0 ^ ((row & 7) << 3));  // write-side XOR
            float a[4] = {ld[k].x, ld[k].y, ld[k].z, ld[k].w};
            ushort4 H, L;
            unsigned short* hp = (unsigned short*)&H;
            unsigned short* lp = (unsigned short*)&L;
#pragma unroll
            for (int e = 0; e < 4; ++e) {
                unsigned short hb = bf16_rne(a[e]);
                hp[e] = hb;
                lp[e] = bf16_rne(a[e] - bf16_f(hb));
            }
            *(ushort4*)(dh + off) = H;
            *(ushort4*)(dl + off) = L;
        }
    };

    auto compute = [&](const unsigned short* bh_, const unsigned short* bl_,
                       int n) {
        // B-frags: only this wave's 32-row slice (rows 32wv .. 32wv+31)
        short8v Bh0[2], Bl0[2], Bh1[2], Bl1[2];
#pragma unroll
        for (int t8l = 0; t8l < 2; ++t8l) {
            int row = 32 * wv + 16 * t8l + lm;
            int c0 = row * 64 + ((kg * 8) ^ sw);
            int c1 = row * 64 + (((kg * 8) + 32) ^ sw);
            Bh0[t8l] = *(const short8v*)(bh_ + c0);
            Bl0[t8l] = *(const short8v*)(bl_ + c0);
            Bh1[t8l] = *(const short8v*)(bh_ + c1);
            Bl1[t8l] = *(const short8v*)(bl_ + c1);
        }
        // A-frags: 2-deep prefetch over 4 b-blocks
        short8v Ah0[2], Al0[2], Ah1[2], Al1[2];
        {
            const size_t xo = ((size_t)lm * Nn + n) * Ii + kg * 8;
            Ah0[0] = *(const short8v*)(xh + xo);
            Al0[0] = *(const short8v*)(xl + xo);
            Ah1[0] = *(const short8v*)(xh + xo + 32);
            Al1[0] = *(const short8v*)(xl + xo + 32);
        }
#pragma unroll
        for (int bq = 0; bq < 4; ++bq) {
            const int s = bq & 1;
            if (bq < 3) {
                const size_t xo =
                    ((size_t)(16 * (bq + 1) + lm) * Nn + n) * Ii + kg * 8;
                Ah0[s ^ 1] = *(const short8v*)(xh + xo);
                Al0[s ^ 1] = *(const short8v*)(xl + xo);
                Ah1[s ^ 1] = *(const short8v*)(xh + xo + 32);
                Al1[s ^ 1] = *(const short8v*)(xl + xo + 32);
            }
            float u[2][4];
#pragma unroll
            for (int t8l = 0; t8l < 2; ++t8l) {
                float4v a;
                if constexpr (MODE == 0) a = acc4[bq][t8l];
                else a = (float4v){0.f, 0.f, 0.f, 0.f};
                a = __builtin_amdgcn_mfma_f32_16x16x32_bf16(Ah0[s], Bh0[t8l], a, 0, 0, 0);
                a = __builtin_amdgcn_mfma_f32_16x16x32_bf16(Al0[s], Bh0[t8l], a, 0, 0, 0);
                a = __builtin_amdgcn_mfma_f32_16x16x32_bf16(Ah0[s], Bl0[t8l], a, 0, 0, 0);
                a = __builtin_amdgcn_mfma_f32_16x16x32_bf16(Ah1[s], Bh1[t8l], a, 0, 0, 0);
                a = __builtin_amdgcn_mfma_f32_16x16x32_bf16(Al1[s], Bh1[t8l], a, 0, 0, 0);
                a = __builtin_amdgcn_mfma_f32_16x16x32_bf16(Ah1[s], Bl1[t8l], a, 0, 0, 0);
                if constexpr (MODE == 0) {
                    acc4[bq][t8l] = a;
                } else {
                    u[t8l][0] = a[0]; u[t8l][1] = a[1];
                    u[t8l][2] = a[2]; u[t8l][3] = a[3];
                }
            }
            if constexpr (MODE == 1) {
                // softmax over 32 c = 2 in-lane (t8l) x 16 lanes (xor 1,2,4,8)
#pragma unroll
                for (int r = 0; r < 4; ++r) {
                    float l0 = u[0][r] * Vreg[bq][0][r];
                    float l1 = u[1][r] * Vreg[bq][1][r];
                    float m = fmaxf(l0, l1);
                    m = fmaxf(m, __shfl_xor(m, 1));
                    m = fmaxf(m, __shfl_xor(m, 2));
                    m = fmaxf(m, __shfl_xor(m, 4));
                    m = fmaxf(m, __shfl_xor(m, 8));
                    float e0 = __expf(l0 - m);
                    float e1 = __expf(l1 - m);
                    float Z = e0 + e1;
                    Z += __shfl_xor(Z, 1);
                    Z += __shfl_xor(Z, 2);
                    Z += __shfl_xor(Z, 4);
                    Z += __shfl_xor(Z, 8);
                    float rz = 1.f / Z;
                    accs[bq][0][r] = fmaf(e0 * rz, u[0][r], accs[bq][0][r]);
                    accs[bq][1][r] = fmaf(e1 * rz, u[1][r], accs[bq][1][r]);
                }
            }
        }
    };

    // Prologue: buf0 <- n0 (via L0); L1 <- n0+1
    issue(n0, L0);
    writebuf(sh[0], sl[0], L0);
    issue(n0 + 1, L1);
    __syncthreads();

    for (int j = 0; j < CHN; j += 2) {
        writebuf(sh[1], sl[1], L1);            // buf1 <- n0+j+1
        if (j + 2 < CHN) issue(n0 + j + 2, L0);
        compute(sh[0], sl[0], n0 + j);
        __syncthreads();
        if (j + 2 < CHN) writebuf(sh[0], sl[0], L0);
        if (j + 3 < CHN) issue(n0 + j + 3, L1);
        compute(sh[1], sl[1], n0 + j + 1);
        __syncthreads();
    }

    // write per-chunk partials: part[ch][b][c][o]
#pragma unroll
    for (int bq = 0; bq < 4; ++bq)
#pragma unroll
        for (int t8l = 0; t8l < 2; ++t8l)
#pragma unroll
            for (int r = 0; r < 4; ++r) {
                int b = 16 * bq + 4 * kg + r;
                int c = 16 * t8l + lm;
                float val = (MODE == 0) ? acc4[bq][t8l][r] : accs[bq][t8l][r];
                part[(((size_t)ch * Bb + b) * Cc + c) * Oo + o] = val;
            }
}

// ---- reduce partials over chunks; squash; update V / write out -------------
__global__ void reduce_caps(const float* __restrict__ part,
                            float* __restrict__ V, float* __restrict__ out,
                            int mode) {
    int bc = blockIdx.x;       // b*32+c, 2048 blocks
    int o = threadIdx.x;       // 64
    size_t base = (size_t)bc * 64 + o;
    float s = 0.f;
    for (int c = 0; c < NCH; ++c) s += part[(size_t)c * (Bb * Cc * Oo) + base];
    if (mode == 0)      V[base] = squash_elem(s * (1.f / 32.f));
    else if (mode == 1) V[base] += squash_elem(s);
    else                out[base] = squash_elem(s);
}

extern "C" void kernel_launch(void* const* d_in, const int* in_sizes, int n_in,
                              void* d_out, int out_size, void* d_ws, size_t ws_size,
                              hipStream_t stream) {
    const float* x = (const float*)d_in[0];          // [64,1152,64]
    const float* w = (const float*)d_in[1];          // [32,1152,64,64]
    float* out = (float*)d_out;                      // [64,32,64]

    const size_t XE = (size_t)Bb * Nn * Ii;          // 4,718,592
    unsigned short* xh = (unsigned short*)d_ws;
    unsigned short* xl = xh + XE;
    float* part = (float*)(xl + XE);                 // 32*64*32*64 f32 ~ 17 MB
    float* V = part + (size_t)NCH * Bb * Cc * Oo;

    prep_x<<<(int)(XE / 4 / 256), 256, 0, stream>>>(x, xh, xl);

    caps_pass<0><<<dim3(NCH, OT), 256, 0, stream>>>(w, xh, xl, nullptr, part);
    reduce_caps<<<Bb * Cc, 64, 0, stream>>>(part, V, out, 0);   // V = v0
    caps_pass<1><<<dim3(NCH, OT), 256, 0, stream>>>(w, xh, xl, V, part);
    reduce_caps<<<Bb * Cc, 64, 0, stream>>>(part, V, out, 1);   // V += v1
    caps_pass<1><<<dim3(NCH, OT), 256, 0, stream>>>(w, xh, xl, V, part);
    reduce_caps<<<Bb * Cc, 64, 0, stream>>>(part, V, out, 2);   // out = v2
}

// Round 8
// 913.011 us; speedup vs baseline: 1.3555x; 1.3555x over previous
//
#include <hip/hip_runtime.h>
#include <hip/hip_bf16.h>

typedef short short8v __attribute__((ext_vector_type(8)));
typedef float float4v __attribute__((ext_vector_type(4)));

constexpr int Bb = 64;    // batch
constexpr int Cc = 32;    // capsules (softmax axis)
constexpr int Nn = 1152;  // routes
constexpr int Oo = 64;    // out channels
constexpr int Ii = 64;    // in channels
constexpr int NCH = 32;   // n-chunks (grid.x)
constexpr int CHN = 36;   // n per chunk
constexpr int OT  = 16;   // o-tiles (grid.y), 4 o per tile (1 per wave)

__device__ __forceinline__ unsigned short bf16_rne(float f) {
    unsigned u = __float_as_uint(f);
    u += 0x7FFFu + ((u >> 16) & 1u);
    return (unsigned short)(u >> 16);
}
__device__ __forceinline__ float bf16_f(unsigned short h) {
    return __uint_as_float(((unsigned)h) << 16);
}
__device__ __forceinline__ float squash_elem(float s) {
    float sq = s * s;
    return (sq / (1.f + sq)) * s / sqrtf(sq + 1e-8f);
}

// split 8 f32 (two float4) into hi/lo bf16 fragments (RNE both)
__device__ __forceinline__ void split8(const float4& f0, const float4& f1,
                                       short8v& h, short8v& lo) {
    float a[8] = {f0.x, f0.y, f0.z, f0.w, f1.x, f1.y, f1.z, f1.w};
#pragma unroll
    for (int e = 0; e < 8; ++e) {
        unsigned short hb = bf16_rne(a[e]);
        h[e] = (short)hb;
        lo[e] = (short)bf16_rne(a[e] - bf16_f(hb));
    }
}

// ---- pre-split + TRANSPOSE x -> xt[n][b][i] hi/lo bf16 planes --------------
// One block per n; thread t: b = t>>2, 16 consecutive i starting at (t&3)*16.
__global__ __launch_bounds__(256) void prep_xt(const float* __restrict__ x,
                                               unsigned short* __restrict__ xh,
                                               unsigned short* __restrict__ xl) {
    const int n = blockIdx.x, t = threadIdx.x;
    const int b = t >> 2, q = t & 3;
    const float* src = x + ((size_t)b * Nn + n) * Ii + q * 16;
    float4 v0 = *(const float4*)(src);
    float4 v1 = *(const float4*)(src + 4);
    float4 v2 = *(const float4*)(src + 8);
    float4 v3 = *(const float4*)(src + 12);
    short8v h0, l0, h1, l1;
    split8(v0, v1, h0, l0);
    split8(v2, v3, h1, l1);
    size_t dst = (size_t)n * (Bb * Ii) + b * Ii + q * 16;
    *(short8v*)(xh + dst) = h0;
    *(short8v*)(xh + dst + 8) = h1;
    *(short8v*)(xl + dst) = l0;
    *(short8v*)(xl + dst + 8) = l1;
}

// ---- fused pass: BARRIER-FREE. Wave wv owns o = 4*ot+wv; stages its own ----
// 32-row (c) w slice into a private LDS slab; A-frags from coalesced xt.
// MODE 0: acc += u (chained in MFMA C); MODE 1: acc += softmax_c(u*V) * u
template <int MODE>
__global__ __launch_bounds__(256, 2) void caps_pass(
    const float* __restrict__ w, const unsigned short* __restrict__ xh,
    const unsigned short* __restrict__ xl, const float* __restrict__ V,
    float* __restrict__ part) {
    __shared__ unsigned short sh[4 * 32 * 64];  // per-wave 4KB hi slice
    __shared__ unsigned short sl[4 * 32 * 64];  // per-wave 4KB lo slice

    const int t = threadIdx.x;
    const int l = t & 63, wv = t >> 6;
    const int ch = blockIdx.x, ot = blockIdx.y;
    const int o = ot * 4 + wv;
    const int kg = l >> 4, lm = l & 15;
    const int n0 = ch * CHN;
    // staging coords: lane covers w row c=cst, f32 half 'hf' (32 f32 = 128B)
    const int cst = l & 31, hf = l >> 5;
    const float* wlane = w + (((size_t)cst * Nn) * Oo + o) * Ii + hf * 32;
    unsigned short* mysh = sh + wv * (32 * 64);
    unsigned short* mysl = sl + wv * (32 * 64);

    // per-lane V: b = 16bq+4kg+r, c = 16t8l+lm, o fixed
    float Vreg[4][2][4];
    if constexpr (MODE == 1) {
#pragma unroll
        for (int bq = 0; bq < 4; ++bq)
#pragma unroll
            for (int t8l = 0; t8l < 2; ++t8l)
#pragma unroll
                for (int r = 0; r < 4; ++r)
                    Vreg[bq][t8l][r] =
                        V[((size_t)(16 * bq + 4 * kg + r) * Cc + 16 * t8l + lm) * Oo + o];
    }
    float4v acc4[4][2];
    float accs[4][2][4];
#pragma unroll
    for (int bq = 0; bq < 4; ++bq)
#pragma unroll
        for (int t8l = 0; t8l < 2; ++t8l) {
            acc4[bq][t8l] = (float4v){0.f, 0.f, 0.f, 0.f};
#pragma unroll
            for (int r = 0; r < 4; ++r) accs[bq][t8l][r] = 0.f;
        }

    float4 L[8];  // w prefetch registers (one n ahead)
    auto issueW = [&](int n) {
        const float* p = wlane + (size_t)n * (Oo * Ii);
#pragma unroll
        for (int q = 0; q < 8; ++q) L[q] = *(const float4*)(p + q * 4);
    };
    auto writeW = [&]() {
        // 32 f32 -> 4x 16B hi + 4x 16B lo, seg s = hf*4+p, swizzled s^=cst&7
#pragma unroll
        for (int p = 0; p < 4; ++p) {
            short8v H, Lo;
            split8(L[2 * p], L[2 * p + 1], H, Lo);
            int sp = (hf * 4 + p) ^ (cst & 7);
            int off = cst * 64 + sp * 8;
            *(short8v*)(mysh + off) = H;
            *(short8v*)(mysl + off) = Lo;
        }
    };

    // prologue: stage n0 (full latency exposed once)
    issueW(n0);
    writeW();

    for (int j = 0; j < CHN; ++j) {
        const int n = n0 + j;
        if (j + 1 < CHN) issueW(n + 1);  // HBM prefetch: lands during compute

        // B-frags from private LDS slice (swizzled, conflict-minimal)
        short8v Bh0[2], Bl0[2], Bh1[2], Bl1[2];
#pragma unroll
        for (int t8l = 0; t8l < 2; ++t8l) {
            int c = 16 * t8l + lm;
            int off0 = c * 64 + ((kg ^ (lm & 7)) * 8);
            int off1 = c * 64 + (((4 + kg) ^ (lm & 7)) * 8);
            Bh0[t8l] = *(const short8v*)(mysh + off0);
            Bl0[t8l] = *(const short8v*)(mysl + off0);
            Bh1[t8l] = *(const short8v*)(mysh + off1);
            Bl1[t8l] = *(const short8v*)(mysl + off1);
        }

        // A-frags from xt (coalesced 2KB regions), 2-deep across bq
        const unsigned short* xhn = xh + (size_t)n * (Bb * Ii) + kg * 8;
        const unsigned short* xln = xl + (size_t)n * (Bb * Ii) + kg * 8;
        short8v Ah0[2], Al0[2], Ah1[2], Al1[2];
        {
            int rb = lm * Ii;
            Ah0[0] = *(const short8v*)(xhn + rb);
            Al0[0] = *(const short8v*)(xln + rb);
            Ah1[0] = *(const short8v*)(xhn + rb + 32);
            Al1[0] = *(const short8v*)(xln + rb + 32);
        }
#pragma unroll
        for (int bq = 0; bq < 4; ++bq) {
            const int s = bq & 1;
            if (bq < 3) {
                int rb = (16 * (bq + 1) + lm) * Ii;
                Ah0[s ^ 1] = *(const short8v*)(xhn + rb);
                Al0[s ^ 1] = *(const short8v*)(xln + rb);
                Ah1[s ^ 1] = *(const short8v*)(xhn + rb + 32);
                Al1[s ^ 1] = *(const short8v*)(xln + rb + 32);
            }
            float u[2][4];
#pragma unroll
            for (int t8l = 0; t8l < 2; ++t8l) {
                float4v a;
                if constexpr (MODE == 0) a = acc4[bq][t8l];
                else a = (float4v){0.f, 0.f, 0.f, 0.f};
                a = __builtin_amdgcn_mfma_f32_16x16x32_bf16(Ah0[s], Bh0[t8l], a, 0, 0, 0);
                a = __builtin_amdgcn_mfma_f32_16x16x32_bf16(Al0[s], Bh0[t8l], a, 0, 0, 0);
                a = __builtin_amdgcn_mfma_f32_16x16x32_bf16(Ah0[s], Bl0[t8l], a, 0, 0, 0);
                a = __builtin_amdgcn_mfma_f32_16x16x32_bf16(Ah1[s], Bh1[t8l], a, 0, 0, 0);
                a = __builtin_amdgcn_mfma_f32_16x16x32_bf16(Al1[s], Bh1[t8l], a, 0, 0, 0);
                a = __builtin_amdgcn_mfma_f32_16x16x32_bf16(Ah1[s], Bl1[t8l], a, 0, 0, 0);
                if constexpr (MODE == 0) {
                    acc4[bq][t8l] = a;
                } else {
                    u[t8l][0] = a[0]; u[t8l][1] = a[1];
                    u[t8l][2] = a[2]; u[t8l][3] = a[3];
                }
            }
            if constexpr (MODE == 1) {
                // softmax over 32 c = 2 in-lane x 16 lanes (xor 1,2,4,8)
#pragma unroll
                for (int r = 0; r < 4; ++r) {
                    float l0 = u[0][r] * Vreg[bq][0][r];
                    float l1 = u[1][r] * Vreg[bq][1][r];
                    float m = fmaxf(l0, l1);
                    m = fmaxf(m, __shfl_xor(m, 1));
                    m = fmaxf(m, __shfl_xor(m, 2));
                    m = fmaxf(m, __shfl_xor(m, 4));
                    m = fmaxf(m, __shfl_xor(m, 8));
                    float e0 = __expf(l0 - m);
                    float e1 = __expf(l1 - m);
                    float Z = e0 + e1;
                    Z += __shfl_xor(Z, 1);
                    Z += __shfl_xor(Z, 2);
                    Z += __shfl_xor(Z, 4);
                    Z += __shfl_xor(Z, 8);
                    float rz = 1.f / Z;
                    accs[bq][0][r] = fmaf(e0 * rz, u[0][r], accs[bq][0][r]);
                    accs[bq][1][r] = fmaf(e1 * rz, u[1][r], accs[bq][1][r]);
                }
            }
        }

        if (j + 1 < CHN) writeW();  // stage n+1 into private slice (no barrier)
    }

    // write per-chunk partials: part[ch][b][c][o]
#pragma unroll
    for (int bq = 0; bq < 4; ++bq)
#pragma unroll
        for (int t8l = 0; t8l < 2; ++t8l)
#pragma unroll
            for (int r = 0; r < 4; ++r) {
                int b = 16 * bq + 4 * kg + r;
                int c = 16 * t8l + lm;
                float val = (MODE == 0) ? acc4[bq][t8l][r] : accs[bq][t8l][r];
                part[(((size_t)ch * Bb + b) * Cc + c) * Oo + o] = val;
            }
}

// ---- reduce partials over chunks; squash; update V / write out -------------
__global__ void reduce_caps(const float* __restrict__ part,
                            float* __restrict__ V, float* __restrict__ out,
                            int mode) {
    int bc = blockIdx.x;       // b*32+c, 2048 blocks
    int o = threadIdx.x;       // 64
    size_t base = (size_t)bc * 64 + o;
    float s = 0.f;
    for (int c = 0; c < NCH; ++c) s += part[(size_t)c * (Bb * Cc * Oo) + base];
    if (mode == 0)      V[base] = squash_elem(s * (1.f / 32.f));
    else if (mode == 1) V[base] += squash_elem(s);
    else                out[base] = squash_elem(s);
}

extern "C" void kernel_launch(void* const* d_in, const int* in_sizes, int n_in,
                              void* d_out, int out_size, void* d_ws, size_t ws_size,
                              hipStream_t stream) {
    const float* x = (const float*)d_in[0];          // [64,1152,64]
    const float* w = (const float*)d_in[1];          // [32,1152,64,64]
    float* out = (float*)d_out;                      // [64,32,64]

    const size_t XE = (size_t)Bb * Nn * Ii;          // 4,718,592
    unsigned short* xh = (unsigned short*)d_ws;      // xt hi [n][b][i]
    unsigned short* xl = xh + XE;                    // xt lo
    float* part = (float*)(xl + XE);                 // 32*64*32*64 f32 ~ 17 MB
    float* V = part + (size_t)NCH * Bb * Cc * Oo;

    prep_xt<<<Nn, 256, 0, stream>>>(x, xh, xl);

    caps_pass<0><<<dim3(NCH, OT), 256, 0, stream>>>(w, xh, xl, nullptr, part);
    reduce_caps<<<Bb * Cc, 64, 0, stream>>>(part, V, out, 0);   // V = v0
    caps_pass<1><<<dim3(NCH, OT), 256, 0, stream>>>(w, xh, xl, V, part);
    reduce_caps<<<Bb * Cc, 64, 0, stream>>>(part, V, out, 1);   // V += v1
    caps_pass<1><<<dim3(NCH, OT), 256, 0, stream>>>(w, xh, xl, V, part);
    reduce_caps<<<Bb * Cc, 64, 0, stream>>>(part, V, out, 2);   // out = v2
}

// Round 9
// 496.387 us; speedup vs baseline: 2.4931x; 1.8393x over previous
//
#include <hip/hip_runtime.h>
#include <hip/hip_bf16.h>

typedef short short8v __attribute__((ext_vector_type(8)));
typedef float float4v __attribute__((ext_vector_type(4)));

constexpr int Bb = 64;    // batch
constexpr int Cc = 32;    // capsules (softmax axis)
constexpr int Nn = 1152;  // routes
constexpr int Oo = 64;    // out channels
constexpr int Ii = 64;    // in channels
constexpr int NCH = 32;   // n-chunks (grid.x)
constexpr int CHN = 36;   // n per chunk (even -> clean 2-unroll)
constexpr int OT  = 16;   // o-tiles (grid.y), 4 o per tile

__device__ __forceinline__ unsigned short bf16_rne(float f) {
    unsigned u = __float_as_uint(f);
    u += 0x7FFFu + ((u >> 16) & 1u);
    return (unsigned short)(u >> 16);
}
__device__ __forceinline__ float bf16_f(unsigned short h) {
    return __uint_as_float(((unsigned)h) << 16);
}
__device__ __forceinline__ float squash_elem(float s) {
    float sq = s * s;
    return (sq / (1.f + sq)) * s / sqrtf(sq + 1e-8f);
}

// barrier WITHOUT vmcnt drain: DS ops complete (buffer safety) but global
// prefetch loads stay in flight across the barrier (T4 / m201 pattern).
__device__ __forceinline__ void barrier_nodrain() {
    asm volatile("s_waitcnt lgkmcnt(0)" ::: "memory");
    __builtin_amdgcn_s_barrier();
    asm volatile("" ::: "memory");
}

// split 8 f32 (two float4) into hi/lo bf16 fragments (RNE both)
__device__ __forceinline__ void split8(const float4& f0, const float4& f1,
                                       short8v& h, short8v& lo) {
    float a[8] = {f0.x, f0.y, f0.z, f0.w, f1.x, f1.y, f1.z, f1.w};
#pragma unroll
    for (int e = 0; e < 8; ++e) {
        unsigned short hb = bf16_rne(a[e]);
        h[e] = (short)hb;
        lo[e] = (short)bf16_rne(a[e] - bf16_f(hb));
    }
}

// ---- pre-split + TRANSPOSE x -> xt[n][b][i] hi/lo bf16 planes --------------
__global__ __launch_bounds__(256) void prep_xt(const float* __restrict__ x,
                                               unsigned short* __restrict__ xh,
                                               unsigned short* __restrict__ xl) {
    const int n = blockIdx.x, t = threadIdx.x;
    const int b = t >> 2, q = t & 3;
    const float* src = x + ((size_t)b * Nn + n) * Ii + q * 16;
    float4 v0 = *(const float4*)(src);
    float4 v1 = *(const float4*)(src + 4);
    float4 v2 = *(const float4*)(src + 8);
    float4 v3 = *(const float4*)(src + 12);
    short8v h0, l0, h1, l1;
    split8(v0, v1, h0, l0);
    split8(v2, v3, h1, l1);
    size_t dst = (size_t)n * (Bb * Ii) + b * Ii + q * 16;
    *(short8v*)(xh + dst) = h0;
    *(short8v*)(xh + dst + 8) = h1;
    *(short8v*)(xl + dst) = l0;
    *(short8v*)(xl + dst + 8) = l1;
}

// ---- fused pass: recompute u via split-bf16 MFMA, route, partial-reduce ----
// MODE 0: acc += u (chained in MFMA C); MODE 1: acc += softmax_c(u*V) * u
// Block (n-chunk, o-quad): 64 b x 32 c x 4 o. LDS XOR-swizzled (T2).
// Depth-2 register pipeline + lgkm-only barriers: prefetch loads survive
// the barrier -> HBM issue stays continuous.
template <int MODE>
__global__ __launch_bounds__(256, 2) void caps_pass(
    const float* __restrict__ w, const unsigned short* __restrict__ xh,
    const unsigned short* __restrict__ xl, const float* __restrict__ V,
    float* __restrict__ part) {
    __shared__ unsigned short sh[2][128 * 64];  // hi plane, [col][i^swz]
    __shared__ unsigned short sl[2][128 * 64];  // lo plane

    const int t = threadIdx.x;
    const int l = t & 63, wv = t >> 6;
    const int ch = blockIdx.x, ot = blockIdx.y;
    const int obase = ot * 4;
    const int kg = l >> 4;          // lane quarter: b sub-row / k-group
    const int lm = l & 15;
    const int n0 = ch * CHN;
    const int sw = (lm & 7) << 3;   // read-side XOR (ushort units)

    // per-lane V: b = 16wv+4kg+r, c = 4t8+((l>>2)&3), o = obase+(l&3)
    float Vreg[8][4];
    if constexpr (MODE == 1) {
#pragma unroll
        for (int t8 = 0; t8 < 8; ++t8)
#pragma unroll
            for (int r = 0; r < 4; ++r) {
                int b = 16 * wv + 4 * kg + r;
                int c = 4 * t8 + ((l >> 2) & 3);
                int o = obase + (l & 3);
                Vreg[t8][r] = V[((size_t)b * Cc + c) * Oo + o];
            }
    }
    float4v acc4[8];   // MODE 0 accumulators (chained through MFMA C)
    float accs[8][4];  // MODE 1 accumulators
#pragma unroll
    for (int t8 = 0; t8 < 8; ++t8) {
        acc4[t8] = (float4v){0.f, 0.f, 0.f, 0.f};
#pragma unroll
        for (int r = 0; r < 4; ++r) accs[t8][r] = 0.f;
    }

    // staging: per thread 8 cols x 16B f32; col = (t>>4)+16k, i0 = (t&15)*4
    const int i0 = (t & 15) * 4;
    const int colb = t >> 4;
    float4 L0[8], L1[8];

    auto issue = [&](int n, float4(&ld)[8]) {
#pragma unroll
        for (int k = 0; k < 8; ++k) {
            int col = colb + 16 * k;
            int c = col >> 2, olc = col & 3;
            ld[k] = *(const float4*)(
                w + (((size_t)c * Nn + n) * Oo + obase + olc) * Ii + i0);
        }
    };
    auto writebuf = [&](unsigned short* dh, unsigned short* dl,
                        const float4(&ld)[8]) {
#pragma unroll
        for (int k = 0; k < 8; ++k) {
            int col = colb + 16 * k;
            int off = col * 64 + (i0 ^ ((col & 7) << 3));  // write-side XOR
            short8v H, Lo;
            split8(ld[k], *(const float4*)nullptr == *(const float4*)nullptr
                              ? ld[k]
                              : ld[k],
                   H, Lo);  // placeholder avoided below
        }
    };
    (void)writebuf;  // replaced by writebuf2 (split pairs correctly)

    auto writebuf2 = [&](unsigned short* dh, unsigned short* dl,
                         const float4(&ld)[8]) {
#pragma unroll
        for (int k = 0; k < 8; ++k) {
            int col = colb + 16 * k;
            int off = col * 64 + (i0 ^ ((col & 7) << 3));
            float a[4] = {ld[k].x, ld[k].y, ld[k].z, ld[k].w};
            ushort4 H, L;
            unsigned short* hp = (unsigned short*)&H;
            unsigned short* lp = (unsigned short*)&L;
#pragma unroll
            for (int e = 0; e < 4; ++e) {
                unsigned short hb = bf16_rne(a[e]);
                hp[e] = hb;
                lp[e] = bf16_rne(a[e] - bf16_f(hb));
            }
            *(ushort4*)(dh + off) = H;
            *(ushort4*)(dl + off) = L;
        }
    };

    auto compute = [&](const unsigned short* bh_, const unsigned short* bl_,
                       int n) {
        // A-frags from xt[n][b][i]: wave reads one contiguous 2KB region
        const size_t xoff =
            (size_t)n * (Bb * Ii) + (16 * wv + lm) * Ii + kg * 8;
        short8v ah0 = *(const short8v*)(xh + xoff);
        short8v al0 = *(const short8v*)(xl + xoff);
        short8v ah1 = *(const short8v*)(xh + xoff + 32);
        short8v al1 = *(const short8v*)(xl + xoff + 32);

        float u[8][4];
#pragma unroll
        for (int t8 = 0; t8 < 8; ++t8) {
            int row = 16 * t8 + lm;
            int c0 = row * 64 + ((kg * 8) ^ sw);
            int c1 = row * 64 + (((kg * 8) + 32) ^ sw);
            short8v bh0 = *(const short8v*)(bh_ + c0);
            short8v bl0 = *(const short8v*)(bl_ + c0);
            short8v bh1 = *(const short8v*)(bh_ + c1);
            short8v bl1 = *(const short8v*)(bl_ + c1);
            float4v a;
            if constexpr (MODE == 0) a = acc4[t8];
            else a = (float4v){0.f, 0.f, 0.f, 0.f};
            a = __builtin_amdgcn_mfma_f32_16x16x32_bf16(ah0, bh0, a, 0, 0, 0);
            a = __builtin_amdgcn_mfma_f32_16x16x32_bf16(al0, bh0, a, 0, 0, 0);
            a = __builtin_amdgcn_mfma_f32_16x16x32_bf16(ah0, bl0, a, 0, 0, 0);
            a = __builtin_amdgcn_mfma_f32_16x16x32_bf16(ah1, bh1, a, 0, 0, 0);
            a = __builtin_amdgcn_mfma_f32_16x16x32_bf16(al1, bh1, a, 0, 0, 0);
            a = __builtin_amdgcn_mfma_f32_16x16x32_bf16(ah1, bl1, a, 0, 0, 0);
            if constexpr (MODE == 0) {
                acc4[t8] = a;
            } else {
                u[t8][0] = a[0]; u[t8][1] = a[1];
                u[t8][2] = a[2]; u[t8][3] = a[3];
            }
        }
        if constexpr (MODE == 1) {
            // softmax over 32 c = 8 in-lane (t8) x 4 lanes (xor 4, 8)
#pragma unroll
            for (int r = 0; r < 4; ++r) {
                float m = -1e30f;
#pragma unroll
                for (int t8 = 0; t8 < 8; ++t8)
                    m = fmaxf(m, u[t8][r] * Vreg[t8][r]);
                m = fmaxf(m, __shfl_xor(m, 4));
                m = fmaxf(m, __shfl_xor(m, 8));
                float Z = 0.f;
#pragma unroll
                for (int t8 = 0; t8 < 8; ++t8) {
                    float e = __expf(u[t8][r] * Vreg[t8][r] - m);
                    Z += e;
                    u[t8][r] *= e;  // u now holds e*u
                }
                Z += __shfl_xor(Z, 4);
                Z += __shfl_xor(Z, 8);
                float rz = 1.f / Z;
#pragma unroll
                for (int t8 = 0; t8 < 8; ++t8) accs[t8][r] += u[t8][r] * rz;
            }
        }
    };

    // Prologue: buf0 <- n0 (via L0); L1 <- n0+1
    issue(n0, L0);
    writebuf2(sh[0], sl[0], L0);
    issue(n0 + 1, L1);
    barrier_nodrain();

    // Invariant at top of even step j: buf0 holds n0+j, L1 holds n0+j+1.
    for (int j = 0; j < CHN; j += 2) {
        // even step
        writebuf2(sh[1], sl[1], L1);           // buf1 <- n0+j+1
        if (j + 2 < CHN) issue(n0 + j + 2, L0);
        compute(sh[0], sl[0], n0 + j);
        barrier_nodrain();
        // odd step: buf1 holds n0+j+1, L0 holds n0+j+2
        if (j + 2 < CHN) writebuf2(sh[0], sl[0], L0);
        if (j + 3 < CHN) issue(n0 + j + 3, L1);
        compute(sh[1], sl[1], n0 + j + 1);
        barrier_nodrain();
    }

    // write per-chunk partials: part[ch][b][c][o]
#pragma unroll
    for (int t8 = 0; t8 < 8; ++t8)
#pragma unroll
        for (int r = 0; r < 4; ++r) {
            int b = 16 * wv + 4 * kg + r;
            int c = 4 * t8 + ((l >> 2) & 3);
            int o = obase + (l & 3);
            float val = (MODE == 0) ? acc4[t8][r] : accs[t8][r];
            part[(((size_t)ch * Bb + b) * Cc + c) * Oo + o] = val;
        }
}

// ---- reduce partials over chunks; squash; update V / write out -------------
__global__ void reduce_caps(const float* __restrict__ part,
                            float* __restrict__ V, float* __restrict__ out,
                            int mode) {
    int bc = blockIdx.x;       // b*32+c, 2048 blocks
    int o = threadIdx.x;       // 64
    size_t base = (size_t)bc * 64 + o;
    float s = 0.f;
    for (int c = 0; c < NCH; ++c) s += part[(size_t)c * (Bb * Cc * Oo) + base];
    if (mode == 0)      V[base] = squash_elem(s * (1.f / 32.f));
    else if (mode == 1) V[base] += squash_elem(s);
    else                out[base] = squash_elem(s);
}

extern "C" void kernel_launch(void* const* d_in, const int* in_sizes, int n_in,
                              void* d_out, int out_size, void* d_ws, size_t ws_size,
                              hipStream_t stream) {
    const float* x = (const float*)d_in[0];          // [64,1152,64]
    const float* w = (const float*)d_in[1];          // [32,1152,64,64]
    float* out = (float*)d_out;                      // [64,32,64]

    const size_t XE = (size_t)Bb * Nn * Ii;          // 4,718,592
    unsigned short* xh = (unsigned short*)d_ws;      // xt hi [n][b][i]
    unsigned short* xl = xh + XE;                    // xt lo
    float* part = (float*)(xl + XE);                 // 32*64*32*64 f32 ~ 17 MB
    float* V = part + (size_t)NCH * Bb * Cc * Oo;

    prep_xt<<<Nn, 256, 0, stream>>>(x, xh, xl);

    caps_pass<0><<<dim3(NCH, OT), 256, 0, stream>>>(w, xh, xl, nullptr, part);
    reduce_caps<<<Bb * Cc, 64, 0, stream>>>(part, V, out, 0);   // V = v0
    caps_pass<1><<<dim3(NCH, OT), 256, 0, stream>>>(w, xh, xl, V, part);
    reduce_caps<<<Bb * Cc, 64, 0, stream>>>(part, V, out, 1);   // V += v1
    caps_pass<1><<<dim3(NCH, OT), 256, 0, stream>>>(w, xh, xl, V, part);
    reduce_caps<<<Bb * Cc, 64, 0, stream>>>(part, V, out, 2);   // out = v2
}